// Round 11
// baseline (233.671 us; speedup 1.0000x reference)
//
#include <hip/hip_runtime.h>

// CausalAttention: B=4, S=2048, D=1024, single head over full D.
// R15 = R14 + qkv moves to the BK=32 double-buffered counted core (shared
// with qk) at 32 KB LDS / launch_bounds(256,4) -> 4 blocks/CU (was BK=64 @
// 2/CU, Occupancy 19%, MfmaUtil 29% — latency-bound). Same lever that took
// qk 60->45us in R12. Everything else identical to R14: qk/pv XCD-chunk
// swizzles (panel groups pinned to one XCD L2), pv paired j & 31-j at 3/CU,
// natural order for qkv's grid (its R11 swizzle was 4x FETCH).

typedef __attribute__((ext_vector_type(8))) _Float16 f16x8;
typedef __attribute__((ext_vector_type(4))) _Float16 f16x4;
typedef __attribute__((ext_vector_type(4))) float f32x4;

#define NB   4
#define SEQ  2048
#define DIM  1024
#define SCL  0.03125f   // 1/sqrt(1024)
#define PBATCH (136 * 16384)   // packed P elems per batch (tri(16) tiles)

__device__ __forceinline__ void gll16(const _Float16* g, _Float16* l) {
  __builtin_amdgcn_global_load_lds(
      (__attribute__((address_space(1))) void*)(g),
      (__attribute__((address_space(3))) void*)(l), 16, 0, 0);
}

// ---------------- BK=64 double-buffered 2-phase core (pv) ----------------
// As [2][AR][64], Bs [2][BR][64] fp16. Swizzle chunk' = chunk ^ (row&7).
// Counted boundary wait vmcnt(LA+LB): prev tile landed, next in flight.
template<int AR, int BR>
__device__ __forceinline__ void gemm_core64_db(
    const _Float16* __restrict__ A, int lda,
    const _Float16* __restrict__ Bm, int ldb,
    int K, _Float16* As, _Float16* Bs, f32x4 acc[AR/32][BR/32])
{
  constexpr int LA = AR / 32;
  constexpr int LB = BR / 32;
  constexpr int MI = AR / 32;
  constexpr int NI = BR / 32;
  constexpr int AHALF = AR * 64;
  constexpr int BHALF = BR * 64;

  const int t    = threadIdx.x;
  const int wv   = t >> 6;
  const int ln   = t & 63;
  const int lr   = ln & 15;
  const int lq   = ln >> 4;
  const int rsub = ln >> 3;
  const int colb = (((ln & 7) ^ rsub) * 8);

  const _Float16* ga[LA]; _Float16* dA[LA];
  const _Float16* gb[LB]; _Float16* dB[LB];
#pragma unroll
  for (int l = 0; l < LA; ++l) {
    const int row = (4 * l + wv) * 8 + rsub;
    ga[l] = A + row * lda + colb;
    dA[l] = As + (4 * l + wv) * 512;
  }
#pragma unroll
  for (int l = 0; l < LB; ++l) {
    const int row = (4 * l + wv) * 8 + rsub;
    gb[l] = Bm + row * ldb + colb;
    dB[l] = Bs + (4 * l + wv) * 512;
  }

  const int swzr = lr & 7;
  const int ra = (((wv & 1) * (AR / 2)) + lr) * 64;
  const int rb = (((wv >> 1) * (BR / 2)) + lr) * 64;
  const int c0 = ((0 * 4 + lq) ^ swzr) * 8;
  const int c1 = ((1 * 4 + lq) ^ swzr) * 8;

  auto compute = [&](int half) {
    const _Float16* pa = As + half * AHALF + ra;
    const _Float16* pb = Bs + half * BHALF + rb;
    f16x8 af[MI][2], bf[NI][2];
#pragma unroll
    for (int mi = 0; mi < MI; ++mi) {
      af[mi][0] = *(const f16x8*)(pa + mi * 1024 + c0);
      af[mi][1] = *(const f16x8*)(pa + mi * 1024 + c1);
    }
#pragma unroll
    for (int ni = 0; ni < NI; ++ni) {
      bf[ni][0] = *(const f16x8*)(pb + ni * 1024 + c0);
      bf[ni][1] = *(const f16x8*)(pb + ni * 1024 + c1);
    }
#pragma unroll
    for (int ks = 0; ks < 2; ++ks)
#pragma unroll
      for (int mi = 0; mi < MI; ++mi)
#pragma unroll
        for (int ni = 0; ni < NI; ++ni)
          acc[mi][ni] = __builtin_amdgcn_mfma_f32_16x16x32_f16(
              af[mi][ks], bf[ni][ks], acc[mi][ni], 0, 0, 0);
  };

#pragma unroll
  for (int l = 0; l < LA; ++l) gll16(ga[l], dA[l]);
#pragma unroll
  for (int l = 0; l < LB; ++l) gll16(gb[l], dB[l]);

  int cur = 0;
  for (int k0 = 64; k0 < K; k0 += 64) {
    const int nxt = cur ^ 1;
#pragma unroll
    for (int l = 0; l < LA; ++l) gll16(ga[l] + k0, dA[l] + nxt * AHALF);
#pragma unroll
    for (int l = 0; l < LB; ++l) gll16(gb[l] + k0, dB[l] + nxt * BHALF);
    if constexpr (LA + LB == 8)
      asm volatile("s_waitcnt vmcnt(8)" ::: "memory");
    else
      asm volatile("s_waitcnt vmcnt(6)" ::: "memory");
    __builtin_amdgcn_s_barrier();
    compute(cur);
    __builtin_amdgcn_s_barrier();
    cur = nxt;
  }
  asm volatile("s_waitcnt vmcnt(0)" ::: "memory");
  __builtin_amdgcn_s_barrier();
  compute(cur);
}

// ---------------- BK=32 double-buffered counted core (qkv, qk) ------------
// As/Bs [2][128][32] fp16 (16 KB each; 32 KB total -> 4 blocks/CU).
// Per K-step: 4 gll16, vmcnt(4), barrier, 8 ds_read_b128, 16 MFMA, barrier.
__device__ __forceinline__ void gemm_core32_db(
    const _Float16* __restrict__ A, int lda,
    const _Float16* __restrict__ Bm, int ldb,
    int K, _Float16* As, _Float16* Bs, f32x4 acc[4][4])
{
  const int t    = threadIdx.x;
  const int wv   = t >> 6;
  const int ln   = t & 63;
  const int lr   = ln & 15;
  const int lq   = ln >> 4;
  const int row0 = t >> 2;                          // 0..63
  const int colb = (((t & 3) ^ ((row0 >> 1) & 3)) * 8);

  const _Float16* ga0 = A  + row0 * lda + colb;
  const _Float16* ga1 = ga0 + (size_t)64 * lda;
  const _Float16* gb0 = Bm + row0 * ldb + colb;
  const _Float16* gb1 = gb0 + (size_t)64 * ldb;
  const int dst = wv * 512;

  const int swz = (lr >> 1) & 3;
  const int ra  = ((wv & 1) * 64 + lr) * 32 + ((lq ^ swz) * 8);
  const int rb  = ((wv >> 1) * 64 + lr) * 32 + ((lq ^ swz) * 8);

  auto stage = [&](int k0, int buf) {
    gll16(ga0 + k0, As + buf + dst);
    gll16(ga1 + k0, As + buf + dst + 2048);
    gll16(gb0 + k0, Bs + buf + dst);
    gll16(gb1 + k0, Bs + buf + dst + 2048);
  };
  auto compute = [&](int buf) {
    f16x8 af[4], bf[4];
#pragma unroll
    for (int mi = 0; mi < 4; ++mi) af[mi] = *(const f16x8*)(As + buf + ra + mi * 512);
#pragma unroll
    for (int ni = 0; ni < 4; ++ni) bf[ni] = *(const f16x8*)(Bs + buf + rb + ni * 512);
#pragma unroll
    for (int mi = 0; mi < 4; ++mi)
#pragma unroll
      for (int ni = 0; ni < 4; ++ni)
        acc[mi][ni] = __builtin_amdgcn_mfma_f32_16x16x32_f16(
            af[mi], bf[ni], acc[mi][ni], 0, 0, 0);
  };

  stage(0, 0);
  int cur = 0;
  for (int k0 = 32; k0 < K; k0 += 32) {
    const int nxt = cur ^ 1;
    stage(k0, nxt * 4096);
    asm volatile("s_waitcnt vmcnt(4)" ::: "memory");  // prev step landed
    __builtin_amdgcn_s_barrier();
    compute(cur * 4096);
    __builtin_amdgcn_s_barrier();
    cur = nxt;
  }
  asm volatile("s_waitcnt vmcnt(0)" ::: "memory");
  __builtin_amdgcn_s_barrier();
  compute(cur * 4096);
}

// one kernel converts x, Wq, Wk, Wv (blockIdx.y selects segment)
__global__ __launch_bounds__(256) void cvt_all(
    const float* __restrict__ x, const float* __restrict__ Wq,
    const float* __restrict__ Wk, const float* __restrict__ Wv,
    _Float16* __restrict__ xb, _Float16* __restrict__ Wb)
{
  const float* src; _Float16* dst; int n;
  const int M1 = 1024 * 1024;
  switch (blockIdx.y) {
    case 0: src = x;  dst = xb;          n = NB * SEQ * DIM; break;
    case 1: src = Wq; dst = Wb;          n = M1; break;
    case 2: src = Wk; dst = Wb + M1;     n = M1; break;
    default: src = Wv; dst = Wb + 2*M1;  n = M1; break;
  }
  int i = (blockIdx.x * 256 + threadIdx.x) * 4;
  const int stride = gridDim.x * 256 * 4;
  for (; i < n; i += stride) {
    const float4 v = *(const float4*)(src + i);
    f16x4 o;
    o.x = (_Float16)v.x; o.y = (_Float16)v.y; o.z = (_Float16)v.z; o.w = (_Float16)v.w;
    *(f16x4*)(dst + i) = o;
  }
}

// z=0: Q -> Qb; z=1: K -> Kb; z=2: V -> Vt [b][d][s] (transposed).
// BK=32 core, 32 KB LDS, 4 blocks/CU (1536 blocks = 1.5 overlapped rounds).
// Natural block order (R11 showed an XCD swizzle here is 4x FETCH).
__global__ __launch_bounds__(256, 4) void qkv_gemm(
    const _Float16* __restrict__ xb, const _Float16* __restrict__ Wb,
    const float* __restrict__ bq, const float* __restrict__ bk,
    const float* __restrict__ bv,
    _Float16* __restrict__ Qb, _Float16* __restrict__ Kb, _Float16* __restrict__ Vt)
{
  __shared__ _Float16 As[8192];   // 2 x 128 x 32
  __shared__ _Float16 Bs[8192];
  const int m0 = blockIdx.x * 128;
  const int n0 = blockIdx.y * 128;
  const int z  = blockIdx.z;
  f32x4 acc[4][4];
#pragma unroll
  for (int mi = 0; mi < 4; ++mi)
#pragma unroll
    for (int ni = 0; ni < 4; ++ni) acc[mi][ni] = {0.f, 0.f, 0.f, 0.f};

  gemm_core32_db(xb + (size_t)m0 * DIM, DIM,
                 Wb + (size_t)z * DIM * DIM + (size_t)n0 * DIM, DIM,
                 DIM, As, Bs, acc);

  const int t = threadIdx.x, wv = t >> 6, ln = t & 63, lr = ln & 15, lq = ln >> 4;
  const int wm = wv & 1, wn = wv >> 1;
  const float* bias = (z == 0) ? bq : (z == 1) ? bk : bv;
  if (z < 2) {
    _Float16* O = (z == 0) ? Qb : Kb;
#pragma unroll
    for (int ni = 0; ni < 4; ++ni) {
      const int col = n0 + wn * 64 + ni * 16 + lr;
      const float bb = bias[col];
#pragma unroll
      for (int mi = 0; mi < 4; ++mi) {
        const int r0 = m0 + wm * 64 + mi * 16 + lq * 4;
#pragma unroll
        for (int r = 0; r < 4; ++r)
          O[(size_t)(r0 + r) * DIM + col] = (_Float16)(acc[mi][ni][r] + bb);
      }
    }
  } else {
#pragma unroll
    for (int ni = 0; ni < 4; ++ni) {
      const int col = n0 + wn * 64 + ni * 16 + lr;
      const float bb = bias[col];
#pragma unroll
      for (int mi = 0; mi < 4; ++mi) {
        const int r0 = m0 + wm * 64 + mi * 16 + lq * 4;
        const int b = r0 >> 11, s = r0 & 2047;
        f16x4 pk;
#pragma unroll
        for (int r = 0; r < 4; ++r) pk[r] = (_Float16)(acc[mi][ni][r] + bb);
        *(f16x4*)(Vt + (size_t)b * DIM * SEQ + (size_t)col * SEQ + s) = pk;
      }
    }
  }
}

// Fused QK^T + exp + row-sum. f = x + 136*y in [0,544); s = (f%8)*68 + f/8.
// Same-qt groups (shared 256KB Q panel) contiguous within one 68-chunk ->
// one XCD L2; 68-chunks never straddle a batch (136 = 2*68).
__global__ __launch_bounds__(256, 4) void qk_gemm(
    const _Float16* __restrict__ Qb, const _Float16* __restrict__ Kb,
    _Float16* __restrict__ Pm, float* __restrict__ lsum)
{
  const int f   = blockIdx.x + 136 * blockIdx.y;
  const int s   = (f & 7) * 68 + (f >> 3);
  const int idx = s % 136;
  const int b   = s / 136;
  int qt = 0;
  while ((qt + 1) * (qt + 2) / 2 <= idx) ++qt;
  const int kt = idx - qt * (qt + 1) / 2;
  const int q0 = qt * 128, k0 = kt * 128;

  __shared__ _Float16 As[8192];   // 2 x 128 x 32
  __shared__ _Float16 Bs[8192];
  f32x4 acc[4][4];
#pragma unroll
  for (int mi = 0; mi < 4; ++mi)
#pragma unroll
    for (int ni = 0; ni < 4; ++ni) acc[mi][ni] = {0.f, 0.f, 0.f, 0.f};

  const _Float16* Qp = Qb + (size_t)b * SEQ * DIM + (size_t)q0 * DIM;
  const _Float16* Kp = Kb + (size_t)b * SEQ * DIM + (size_t)k0 * DIM;
  gemm_core32_db(Qp, DIM, Kp, DIM, DIM, As, Bs, acc);

  const int t = threadIdx.x, wv = t >> 6, ln = t & 63, lr = ln & 15, lq = ln >> 4;
  const int wm = wv & 1, wn = wv >> 1;
  const int ldp = (qt + 1) * 128;
  _Float16* scr = Pm + (size_t)b * PBATCH + (size_t)(qt * (qt + 1) / 2) * 16384;
  float* lrow = lsum + b * SEQ;

  float es[4][4];
#pragma unroll
  for (int mi = 0; mi < 4; ++mi)
#pragma unroll
    for (int r = 0; r < 4; ++r) es[mi][r] = 0.f;

#pragma unroll
  for (int ni = 0; ni < 4; ++ni) {
    const int col = k0 + wn * 64 + ni * 16 + lr;
#pragma unroll
    for (int mi = 0; mi < 4; ++mi) {
      const int r0 = q0 + wm * 64 + mi * 16 + lq * 4;
#pragma unroll
      for (int r = 0; r < 4; ++r) {
        const int row = r0 + r;
        const float sc = acc[mi][ni][r] * SCL;
        const float e = (col <= row) ? __expf(fminf(sc, 10.f)) : 0.f;
        scr[(size_t)(row - q0) * ldp + col] = (_Float16)e;
        es[mi][r] += e;
      }
    }
  }
#pragma unroll
  for (int mi = 0; mi < 4; ++mi)
#pragma unroll
    for (int r = 0; r < 4; ++r) {
      float v = es[mi][r];
#pragma unroll
      for (int off = 1; off < 16; off <<= 1) v += __shfl_xor(v, off, 64);
      if (lr == 0) {
        const int row = q0 + wm * 64 + mi * 16 + lq * 4 + r;
        atomicAdd(&lrow[row], v);
      }
    }
}

// out[b][q][d] = (sum_k e[q][k] * Vt[b][d][k]) / l[b][q].
// f = x + 16*(y + 8*z) in [0,512); s = (f%8)*64 + f/8. All 16 p-blocks of a
// (d0,b) group get identical f&7 -> one XCD fetches each 512KB Vt panel.
__global__ __launch_bounds__(256, 3) void pv_gemm(
    const _Float16* __restrict__ Pm, const _Float16* __restrict__ Vt,
    const float* __restrict__ lsum, float* __restrict__ out)
{
  __shared__ _Float16 As[8192];     // 2 x 64 x 64
  __shared__ _Float16 Bs[16384];    // 2 x 128 x 64
  const int f  = blockIdx.x + 16 * (blockIdx.y + 8 * blockIdx.z);
  const int s  = (f & 7) * 64 + (f >> 3);
  const int p  = s & 15;
  const int d0 = ((s >> 4) & 7) * 128;
  const int b  = s >> 7;

  const int t = threadIdx.x, wv = t >> 6, ln = t & 63, lr = ln & 15, lq = ln >> 4;
  const int wm = wv & 1, wn = wv >> 1;
  float* O = out + (size_t)b * SEQ * DIM;
  const float* lrow = lsum + b * SEQ;
  const _Float16* Vp = Vt + (size_t)b * DIM * SEQ + (size_t)d0 * SEQ;

  const int js[2] = { 31 - p, p };  // big subtile first
#pragma unroll
  for (int u = 0; u < 2; ++u) {
    const int j  = js[u];
    const int qt = j >> 1;
    const int q0 = qt * 128 + (j & 1) * 64;
    const int K  = (qt + 1) * 128;  // upper-tri cols hold stored zeros
    if (u) __syncthreads();         // LDS reuse hazard between the pair

    f32x4 acc[2][4];
#pragma unroll
    for (int mi = 0; mi < 2; ++mi)
#pragma unroll
      for (int ni = 0; ni < 4; ++ni) acc[mi][ni] = {0.f, 0.f, 0.f, 0.f};

    const _Float16* Pp = Pm + (size_t)b * PBATCH
        + (size_t)(qt * (qt + 1) / 2) * 16384 + (size_t)(j & 1) * 64 * K;
    gemm_core64_db<64,128>(Pp, K, Vp, SEQ, K, As, Bs, acc);

#pragma unroll
    for (int mi = 0; mi < 2; ++mi) {
      const int r0 = q0 + wm * 32 + mi * 16 + lq * 4;
      const float4 lv = *(const float4*)(lrow + r0);
      const float inv[4] = {1.f / lv.x, 1.f / lv.y, 1.f / lv.z, 1.f / lv.w};
#pragma unroll
      for (int ni = 0; ni < 4; ++ni) {
        const int col = d0 + wn * 64 + ni * 16 + lr;
#pragma unroll
        for (int r = 0; r < 4; ++r)
          O[(size_t)(r0 + r) * DIM + col] = acc[mi][ni][r] * inv[r];
      }
    }
  }
}

extern "C" void kernel_launch(void* const* d_in, const int* in_sizes, int n_in,
                              void* d_out, int out_size, void* d_ws, size_t ws_size,
                              hipStream_t stream) {
  const float* x  = (const float*)d_in[0];
  const float* Wq = (const float*)d_in[1];
  const float* bq = (const float*)d_in[2];
  const float* Wk = (const float*)d_in[3];
  const float* bk = (const float*)d_in[4];
  const float* Wv = (const float*)d_in[5];
  const float* bv = (const float*)d_in[6];
  float* out = (float*)d_out;

  _Float16* w16 = (_Float16*)d_ws;
  const size_t M1 = (size_t)1024 * 1024;
  _Float16* Qb = w16;                 //  0M .. 8M el (16 MB)
  _Float16* Kb = w16 + 8 * M1;        //  8M .. 16M
  _Float16* Vt = w16 + 16 * M1;       // 16M .. 24M  (V transposed [b][d][s])
  _Float16* xb = w16 + 24 * M1;       // 24M .. 32M  (dead after qkv_gemm)
  _Float16* Wb = w16 + 32 * M1;       // 32M .. 35M  (dead after qkv_gemm)
  _Float16* Pm = w16 + 24 * M1;       // packed tri P (17.8 MB), aliases xb
  float*    lsum = (float*)(w16 + 34 * M1);  // 32 KB row sums

  hipMemsetAsync(lsum, 0, NB * SEQ * sizeof(float), stream);
  cvt_all<<<dim3(512, 4), 256, 0, stream>>>(x, Wq, Wk, Wv, xb, Wb);
  qkv_gemm<<<dim3(64, 8, 3), 256, 0, stream>>>(xb, Wb, bq, bk, bv, Qb, Kb, Vt);
  qk_gemm<<<dim3(136, NB), 256, 0, stream>>>(Qb, Kb, Pm, lsum);
  pv_gemm<<<dim3(16, 8, NB), 256, 0, stream>>>(Pm, Vt, lsum, out);
}

// Round 13
// 221.267 us; speedup vs baseline: 1.0561x; 1.0561x over previous
//
#include <hip/hip_runtime.h>

// CausalAttention: B=4, S=2048, D=1024, single head over full D.
// R17 = R14 champion (221.4us) with the lsum init made aliasing-safe.
// ROOT CAUSE of R16's fail: lsum (w16+34M1) aliases Wb's Wv segment
// (Wb+2M1). R16 zeroed it inside cvt_all, racing the Wv-conversion slice
// over the same bytes -> Wv corrupted. Fix: memset lsum BETWEEN qkv and qk
// (Wb dead by then; qk then accumulates from true zero). Kernels identical
// to R14: qkv 2-phase BK=64 dbuf @2/CU natural order; qk BK=32 dbuf @4/CU
// + XCD-chunk swizzle; pv 2-phase <64,128> @3/CU, paired j&31-j, XCD swizzle.

typedef __attribute__((ext_vector_type(8))) _Float16 f16x8;
typedef __attribute__((ext_vector_type(4))) _Float16 f16x4;
typedef __attribute__((ext_vector_type(4))) float f32x4;

#define NB   4
#define SEQ  2048
#define DIM  1024
#define SCL  0.03125f   // 1/sqrt(1024)
#define PBATCH (136 * 16384)   // packed P elems per batch (tri(16) tiles)

__device__ __forceinline__ void gll16(const _Float16* g, _Float16* l) {
  __builtin_amdgcn_global_load_lds(
      (__attribute__((address_space(1))) void*)(g),
      (__attribute__((address_space(3))) void*)(l), 16, 0, 0);
}

// ---------------- BK=64 double-buffered 2-phase core (qkv, pv) ----------------
// As [2][AR][64], Bs [2][BR][64] fp16. Swizzle chunk' = chunk ^ (row&7).
// Counted boundary wait vmcnt(LA+LB): prev tile landed, next in flight.
template<int AR, int BR>
__device__ __forceinline__ void gemm_core64_db(
    const _Float16* __restrict__ A, int lda,
    const _Float16* __restrict__ Bm, int ldb,
    int K, _Float16* As, _Float16* Bs, f32x4 acc[AR/32][BR/32])
{
  constexpr int LA = AR / 32;
  constexpr int LB = BR / 32;
  constexpr int MI = AR / 32;
  constexpr int NI = BR / 32;
  constexpr int AHALF = AR * 64;
  constexpr int BHALF = BR * 64;

  const int t    = threadIdx.x;
  const int wv   = t >> 6;
  const int ln   = t & 63;
  const int lr   = ln & 15;
  const int lq   = ln >> 4;
  const int rsub = ln >> 3;
  const int colb = (((ln & 7) ^ rsub) * 8);

  const _Float16* ga[LA]; _Float16* dA[LA];
  const _Float16* gb[LB]; _Float16* dB[LB];
#pragma unroll
  for (int l = 0; l < LA; ++l) {
    const int row = (4 * l + wv) * 8 + rsub;
    ga[l] = A + row * lda + colb;
    dA[l] = As + (4 * l + wv) * 512;
  }
#pragma unroll
  for (int l = 0; l < LB; ++l) {
    const int row = (4 * l + wv) * 8 + rsub;
    gb[l] = Bm + row * ldb + colb;
    dB[l] = Bs + (4 * l + wv) * 512;
  }

  const int swzr = lr & 7;
  const int ra = (((wv & 1) * (AR / 2)) + lr) * 64;
  const int rb = (((wv >> 1) * (BR / 2)) + lr) * 64;
  const int c0 = ((0 * 4 + lq) ^ swzr) * 8;
  const int c1 = ((1 * 4 + lq) ^ swzr) * 8;

  auto compute = [&](int half) {
    const _Float16* pa = As + half * AHALF + ra;
    const _Float16* pb = Bs + half * BHALF + rb;
    f16x8 af[MI][2], bf[NI][2];
#pragma unroll
    for (int mi = 0; mi < MI; ++mi) {
      af[mi][0] = *(const f16x8*)(pa + mi * 1024 + c0);
      af[mi][1] = *(const f16x8*)(pa + mi * 1024 + c1);
    }
#pragma unroll
    for (int ni = 0; ni < NI; ++ni) {
      bf[ni][0] = *(const f16x8*)(pb + ni * 1024 + c0);
      bf[ni][1] = *(const f16x8*)(pb + ni * 1024 + c1);
    }
#pragma unroll
    for (int ks = 0; ks < 2; ++ks)
#pragma unroll
      for (int mi = 0; mi < MI; ++mi)
#pragma unroll
        for (int ni = 0; ni < NI; ++ni)
          acc[mi][ni] = __builtin_amdgcn_mfma_f32_16x16x32_f16(
              af[mi][ks], bf[ni][ks], acc[mi][ni], 0, 0, 0);
  };

#pragma unroll
  for (int l = 0; l < LA; ++l) gll16(ga[l], dA[l]);
#pragma unroll
  for (int l = 0; l < LB; ++l) gll16(gb[l], dB[l]);

  int cur = 0;
  for (int k0 = 64; k0 < K; k0 += 64) {
    const int nxt = cur ^ 1;
#pragma unroll
    for (int l = 0; l < LA; ++l) gll16(ga[l] + k0, dA[l] + nxt * AHALF);
#pragma unroll
    for (int l = 0; l < LB; ++l) gll16(gb[l] + k0, dB[l] + nxt * BHALF);
    if constexpr (LA + LB == 8)
      asm volatile("s_waitcnt vmcnt(8)" ::: "memory");
    else
      asm volatile("s_waitcnt vmcnt(6)" ::: "memory");
    __builtin_amdgcn_s_barrier();
    compute(cur);
    __builtin_amdgcn_s_barrier();
    cur = nxt;
  }
  asm volatile("s_waitcnt vmcnt(0)" ::: "memory");
  __builtin_amdgcn_s_barrier();
  compute(cur);
}

// ---------------- BK=32 double-buffered counted core (qk) ----------------
// As/Bs [2][128][32] fp16 (16 KB each; 32 KB total -> 4 blocks/CU).
// Per K-step: 4 gll16, vmcnt(4), barrier, 8 ds_read_b128, 16 MFMA, barrier.
__device__ __forceinline__ void gemm_core32_db(
    const _Float16* __restrict__ A, int lda,
    const _Float16* __restrict__ Bm, int ldb,
    int K, _Float16* As, _Float16* Bs, f32x4 acc[4][4])
{
  const int t    = threadIdx.x;
  const int wv   = t >> 6;
  const int ln   = t & 63;
  const int lr   = ln & 15;
  const int lq   = ln >> 4;
  const int row0 = t >> 2;                          // 0..63
  const int colb = (((t & 3) ^ ((row0 >> 1) & 3)) * 8);

  const _Float16* ga0 = A  + row0 * lda + colb;
  const _Float16* ga1 = ga0 + (size_t)64 * lda;
  const _Float16* gb0 = Bm + row0 * ldb + colb;
  const _Float16* gb1 = gb0 + (size_t)64 * ldb;
  const int dst = wv * 512;

  const int swz = (lr >> 1) & 3;
  const int ra  = ((wv & 1) * 64 + lr) * 32 + ((lq ^ swz) * 8);
  const int rb  = ((wv >> 1) * 64 + lr) * 32 + ((lq ^ swz) * 8);

  auto stage = [&](int k0, int buf) {
    gll16(ga0 + k0, As + buf + dst);
    gll16(ga1 + k0, As + buf + dst + 2048);
    gll16(gb0 + k0, Bs + buf + dst);
    gll16(gb1 + k0, Bs + buf + dst + 2048);
  };
  auto compute = [&](int buf) {
    f16x8 af[4], bf[4];
#pragma unroll
    for (int mi = 0; mi < 4; ++mi) af[mi] = *(const f16x8*)(As + buf + ra + mi * 512);
#pragma unroll
    for (int ni = 0; ni < 4; ++ni) bf[ni] = *(const f16x8*)(Bs + buf + rb + ni * 512);
#pragma unroll
    for (int mi = 0; mi < 4; ++mi)
#pragma unroll
      for (int ni = 0; ni < 4; ++ni)
        acc[mi][ni] = __builtin_amdgcn_mfma_f32_16x16x32_f16(
            af[mi], bf[ni], acc[mi][ni], 0, 0, 0);
  };

  stage(0, 0);
  int cur = 0;
  for (int k0 = 32; k0 < K; k0 += 32) {
    const int nxt = cur ^ 1;
    stage(k0, nxt * 4096);
    asm volatile("s_waitcnt vmcnt(4)" ::: "memory");  // prev step landed
    __builtin_amdgcn_s_barrier();
    compute(cur * 4096);
    __builtin_amdgcn_s_barrier();
    cur = nxt;
  }
  asm volatile("s_waitcnt vmcnt(0)" ::: "memory");
  __builtin_amdgcn_s_barrier();
  compute(cur * 4096);
}

// one kernel converts x, Wq, Wk, Wv (blockIdx.y selects segment)
__global__ __launch_bounds__(256) void cvt_all(
    const float* __restrict__ x, const float* __restrict__ Wq,
    const float* __restrict__ Wk, const float* __restrict__ Wv,
    _Float16* __restrict__ xb, _Float16* __restrict__ Wb)
{
  const float* src; _Float16* dst; int n;
  const int M1 = 1024 * 1024;
  switch (blockIdx.y) {
    case 0: src = x;  dst = xb;          n = NB * SEQ * DIM; break;
    case 1: src = Wq; dst = Wb;          n = M1; break;
    case 2: src = Wk; dst = Wb + M1;     n = M1; break;
    default: src = Wv; dst = Wb + 2*M1;  n = M1; break;
  }
  int i = (blockIdx.x * 256 + threadIdx.x) * 4;
  const int stride = gridDim.x * 256 * 4;
  for (; i < n; i += stride) {
    const float4 v = *(const float4*)(src + i);
    f16x4 o;
    o.x = (_Float16)v.x; o.y = (_Float16)v.y; o.z = (_Float16)v.z; o.w = (_Float16)v.w;
    *(f16x4*)(dst + i) = o;
  }
}

// z=0: Q -> Qb; z=1: K -> Kb; z=2: V -> Vt [b][d][s] (transposed).
// Single launch, 1536 blocks @2/CU = 1.5 overlapped rounds. Natural block
// order (R11: an XCD swizzle here is 4x FETCH; R15: BK=32@4/CU is -12us).
__global__ __launch_bounds__(256, 2) void qkv_gemm(
    const _Float16* __restrict__ xb, const _Float16* __restrict__ Wb,
    const float* __restrict__ bq, const float* __restrict__ bk,
    const float* __restrict__ bv,
    _Float16* __restrict__ Qb, _Float16* __restrict__ Kb, _Float16* __restrict__ Vt)
{
  __shared__ _Float16 As[16384];
  __shared__ _Float16 Bs[16384];
  const int m0 = blockIdx.x * 128;
  const int n0 = blockIdx.y * 128;
  const int z  = blockIdx.z;
  f32x4 acc[4][4];
#pragma unroll
  for (int mi = 0; mi < 4; ++mi)
#pragma unroll
    for (int ni = 0; ni < 4; ++ni) acc[mi][ni] = {0.f, 0.f, 0.f, 0.f};

  gemm_core64_db<128,128>(xb + (size_t)m0 * DIM, DIM,
                          Wb + (size_t)z * DIM * DIM + (size_t)n0 * DIM, DIM,
                          DIM, As, Bs, acc);

  const int t = threadIdx.x, wv = t >> 6, ln = t & 63, lr = ln & 15, lq = ln >> 4;
  const int wm = wv & 1, wn = wv >> 1;
  const float* bias = (z == 0) ? bq : (z == 1) ? bk : bv;
  if (z < 2) {
    _Float16* O = (z == 0) ? Qb : Kb;
#pragma unroll
    for (int ni = 0; ni < 4; ++ni) {
      const int col = n0 + wn * 64 + ni * 16 + lr;
      const float bb = bias[col];
#pragma unroll
      for (int mi = 0; mi < 4; ++mi) {
        const int r0 = m0 + wm * 64 + mi * 16 + lq * 4;
#pragma unroll
        for (int r = 0; r < 4; ++r)
          O[(size_t)(r0 + r) * DIM + col] = (_Float16)(acc[mi][ni][r] + bb);
      }
    }
  } else {
#pragma unroll
    for (int ni = 0; ni < 4; ++ni) {
      const int col = n0 + wn * 64 + ni * 16 + lr;
      const float bb = bias[col];
#pragma unroll
      for (int mi = 0; mi < 4; ++mi) {
        const int r0 = m0 + wm * 64 + mi * 16 + lq * 4;
        const int b = r0 >> 11, s = r0 & 2047;
        f16x4 pk;
#pragma unroll
        for (int r = 0; r < 4; ++r) pk[r] = (_Float16)(acc[mi][ni][r] + bb);
        *(f16x4*)(Vt + (size_t)b * DIM * SEQ + (size_t)col * SEQ + s) = pk;
      }
    }
  }
}

// Fused QK^T + exp + row-sum. f = x + 136*y in [0,544); s = (f%8)*68 + f/8.
// Same-qt groups (shared 256KB Q panel) contiguous within one 68-chunk ->
// one XCD L2; 68-chunks never straddle a batch (136 = 2*68).
__global__ __launch_bounds__(256, 4) void qk_gemm(
    const _Float16* __restrict__ Qb, const _Float16* __restrict__ Kb,
    _Float16* __restrict__ Pm, float* __restrict__ lsum)
{
  const int f   = blockIdx.x + 136 * blockIdx.y;
  const int s   = (f & 7) * 68 + (f >> 3);
  const int idx = s % 136;
  const int b   = s / 136;
  int qt = 0;
  while ((qt + 1) * (qt + 2) / 2 <= idx) ++qt;
  const int kt = idx - qt * (qt + 1) / 2;
  const int q0 = qt * 128, k0 = kt * 128;

  __shared__ _Float16 As[8192];   // 2 x 128 x 32
  __shared__ _Float16 Bs[8192];
  f32x4 acc[4][4];
#pragma unroll
  for (int mi = 0; mi < 4; ++mi)
#pragma unroll
    for (int ni = 0; ni < 4; ++ni) acc[mi][ni] = {0.f, 0.f, 0.f, 0.f};

  const _Float16* Qp = Qb + (size_t)b * SEQ * DIM + (size_t)q0 * DIM;
  const _Float16* Kp = Kb + (size_t)b * SEQ * DIM + (size_t)k0 * DIM;
  gemm_core32_db(Qp, DIM, Kp, DIM, DIM, As, Bs, acc);

  const int t = threadIdx.x, wv = t >> 6, ln = t & 63, lr = ln & 15, lq = ln >> 4;
  const int wm = wv & 1, wn = wv >> 1;
  const int ldp = (qt + 1) * 128;
  _Float16* scr = Pm + (size_t)b * PBATCH + (size_t)(qt * (qt + 1) / 2) * 16384;
  float* lrow = lsum + b * SEQ;

  float es[4][4];
#pragma unroll
  for (int mi = 0; mi < 4; ++mi)
#pragma unroll
    for (int r = 0; r < 4; ++r) es[mi][r] = 0.f;

#pragma unroll
  for (int ni = 0; ni < 4; ++ni) {
    const int col = k0 + wn * 64 + ni * 16 + lr;
#pragma unroll
    for (int mi = 0; mi < 4; ++mi) {
      const int r0 = q0 + wm * 64 + mi * 16 + lq * 4;
#pragma unroll
      for (int r = 0; r < 4; ++r) {
        const int row = r0 + r;
        const float sc = acc[mi][ni][r] * SCL;
        const float e = (col <= row) ? __expf(fminf(sc, 10.f)) : 0.f;
        scr[(size_t)(row - q0) * ldp + col] = (_Float16)e;
        es[mi][r] += e;
      }
    }
  }
#pragma unroll
  for (int mi = 0; mi < 4; ++mi)
#pragma unroll
    for (int r = 0; r < 4; ++r) {
      float v = es[mi][r];
#pragma unroll
      for (int off = 1; off < 16; off <<= 1) v += __shfl_xor(v, off, 64);
      if (lr == 0) {
        const int row = q0 + wm * 64 + mi * 16 + lq * 4 + r;
        atomicAdd(&lrow[row], v);
      }
    }
}

// out[b][q][d] = (sum_k e[q][k] * Vt[b][d][k]) / l[b][q].
// f = x + 16*(y + 8*z) in [0,512); s = (f%8)*64 + f/8. All 16 p-blocks of a
// (d0,b) group get identical f&7 -> one XCD fetches each 512KB Vt panel.
__global__ __launch_bounds__(256, 3) void pv_gemm(
    const _Float16* __restrict__ Pm, const _Float16* __restrict__ Vt,
    const float* __restrict__ lsum, float* __restrict__ out)
{
  __shared__ _Float16 As[8192];     // 2 x 64 x 64
  __shared__ _Float16 Bs[16384];    // 2 x 128 x 64
  const int f  = blockIdx.x + 16 * (blockIdx.y + 8 * blockIdx.z);
  const int s  = (f & 7) * 64 + (f >> 3);
  const int p  = s & 15;
  const int d0 = ((s >> 4) & 7) * 128;
  const int b  = s >> 7;

  const int t = threadIdx.x, wv = t >> 6, ln = t & 63, lr = ln & 15, lq = ln >> 4;
  const int wm = wv & 1, wn = wv >> 1;
  float* O = out + (size_t)b * SEQ * DIM;
  const float* lrow = lsum + b * SEQ;
  const _Float16* Vp = Vt + (size_t)b * DIM * SEQ + (size_t)d0 * SEQ;

  const int js[2] = { 31 - p, p };  // big subtile first
#pragma unroll
  for (int u = 0; u < 2; ++u) {
    const int j  = js[u];
    const int qt = j >> 1;
    const int q0 = qt * 128 + (j & 1) * 64;
    const int K  = (qt + 1) * 128;  // upper-tri cols hold stored zeros
    if (u) __syncthreads();         // LDS reuse hazard between the pair

    f32x4 acc[2][4];
#pragma unroll
    for (int mi = 0; mi < 2; ++mi)
#pragma unroll
      for (int ni = 0; ni < 4; ++ni) acc[mi][ni] = {0.f, 0.f, 0.f, 0.f};

    const _Float16* Pp = Pm + (size_t)b * PBATCH
        + (size_t)(qt * (qt + 1) / 2) * 16384 + (size_t)(j & 1) * 64 * K;
    gemm_core64_db<64,128>(Pp, K, Vp, SEQ, K, As, Bs, acc);

#pragma unroll
    for (int mi = 0; mi < 2; ++mi) {
      const int r0 = q0 + wm * 32 + mi * 16 + lq * 4;
      const float4 lv = *(const float4*)(lrow + r0);
      const float inv[4] = {1.f / lv.x, 1.f / lv.y, 1.f / lv.z, 1.f / lv.w};
#pragma unroll
      for (int ni = 0; ni < 4; ++ni) {
        const int col = d0 + wn * 64 + ni * 16 + lr;
#pragma unroll
        for (int r = 0; r < 4; ++r)
          O[(size_t)(r0 + r) * DIM + col] = acc[mi][ni][r] * inv[r];
      }
    }
  }
}

extern "C" void kernel_launch(void* const* d_in, const int* in_sizes, int n_in,
                              void* d_out, int out_size, void* d_ws, size_t ws_size,
                              hipStream_t stream) {
  const float* x  = (const float*)d_in[0];
  const float* Wq = (const float*)d_in[1];
  const float* bq = (const float*)d_in[2];
  const float* Wk = (const float*)d_in[3];
  const float* bk = (const float*)d_in[4];
  const float* Wv = (const float*)d_in[5];
  const float* bv = (const float*)d_in[6];
  float* out = (float*)d_out;

  _Float16* w16 = (_Float16*)d_ws;
  const size_t M1 = (size_t)1024 * 1024;
  _Float16* Qb = w16;                 //  0M .. 8M el (16 MB)
  _Float16* Kb = w16 + 8 * M1;        //  8M .. 16M
  _Float16* Vt = w16 + 16 * M1;       // 16M .. 24M  (V transposed [b][d][s])
  _Float16* xb = w16 + 24 * M1;       // 24M .. 32M  (dead after qkv_gemm)
  _Float16* Wb = w16 + 32 * M1;       // 32M .. 35M  (dead after qkv_gemm)
  _Float16* Pm = w16 + 24 * M1;       // packed tri P (17.8 MB), aliases xb
  float*    lsum = (float*)(w16 + 34 * M1);  // 32 KB; aliases Wv seg of Wb
                                             // (dead after qkv) — zeroed
                                             // only AFTER qkv below.

  cvt_all<<<dim3(512, 4), 256, 0, stream>>>(x, Wq, Wk, Wv, xb, Wb);
  qkv_gemm<<<dim3(64, 8, 3), 256, 0, stream>>>(xb, Wb, bq, bk, bv, Qb, Kb, Vt);
  // Zero lsum only after qkv: lsum aliases Wb's Wv segment, which qkv reads.
  hipMemsetAsync(lsum, 0, NB * SEQ * sizeof(float), stream);
  qk_gemm<<<dim3(136, NB), 256, 0, stream>>>(Qb, Kb, Pm, lsum);
  pv_gemm<<<dim3(16, 8, NB), 256, 0, stream>>>(Pm, Vt, lsum, out);
}